// Round 9
// baseline (478.172 us; speedup 1.0000x reference)
//
#include <hip/hip_runtime.h>
#include <stdint.h>

// SOM forward: x [4096,64] f32, weights [128,128,64] f32 -> bmus [4096,2] int32.
// Three kernels:
//   convert: X,W -> frag-ordered bf16 hi/lo tiles in d_ws + wn=||w||^2 (f32).
//   passA:   barrier-free, LDS-free MFMA streaming. Each wave: 64 rows x one
//            256-m group. X frags persistent in regs; W frags streamed from
//            L2 (4 waves/block share one m-group => L1 reuse). 3-pass hi/lo
//            bf16 split (err ~1e-4 on d^2). Per-lane running (val,m) min;
//            epilogue merges ^4,^8 -> 64-m-class winners, 256 keys/row.
//   passB:   per row, exact rescore of class winners within margin 0.05
//            (fp32 diff, fp64 square-sum, f32 sqrt), tie-break smaller m.
//            Byte-identical to the validated R4/R6 pass.

typedef unsigned short u16;
typedef unsigned int u32;
typedef unsigned long long ull;
typedef __attribute__((ext_vector_type(8))) short bf16x8;
typedef __attribute__((ext_vector_type(4))) float f32x4;

__device__ __forceinline__ u32 enc_f32(float v) {
    u32 u = __float_as_uint(v);
    return (u & 0x80000000u) ? ~u : (u | 0x80000000u);
}
__device__ __forceinline__ float dec_f32(u32 e) {
    u32 u = (e & 0x80000000u) ? (e ^ 0x80000000u) : ~e;
    return __uint_as_float(u);
}
__device__ __forceinline__ ull umin64(ull a, ull b) { return a < b ? a : b; }

// ---------------------------------------------------------------------------
// convert: unit = (row, half-of-64k). W units: 32768, X units: 8192.
// Frag layout per 16-row tile (ushort units): tile*2048 + s*1024 + p*512 +
// lane*8 + j, lane = (r&15) + ((k&31)>>3)*16, s = k>>5, j = k&7, p in {hi,lo}.
// ---------------------------------------------------------------------------
__global__ __launch_bounds__(256)
void som_convert(const float* __restrict__ X, const float* __restrict__ W,
                 u16* __restrict__ Xc, u16* __restrict__ Wc,
                 float* __restrict__ wn) {
    const int u = blockIdx.x * 256 + threadIdx.x;   // 0..40959
    const bool isW = (u < 32768);
    const int v = isW ? u : (u - 32768);
    const int r = v >> 1, h = v & 1;
    const float* src = (isW ? W : X) + (size_t)r * 64 + h * 32;
    u16* dst = isW ? Wc : Xc;

    float4 f[8];
    const float4* sp = (const float4*)src;
#pragma unroll
    for (int i = 0; i < 8; ++i) f[i] = sp[i];

    float p = 0.f;
#pragma unroll
    for (int i = 0; i < 8; ++i)
        p += f[i].x * f[i].x + f[i].y * f[i].y + f[i].z * f[i].z + f[i].w * f[i].w;

    const int bt = r >> 4, lr = r & 15, s = h;
    u16* base = dst + (size_t)bt * 2048 + s * 1024;
#pragma unroll
    for (int g = 0; g < 4; ++g) {
        float e[8] = { f[2 * g].x, f[2 * g].y, f[2 * g].z, f[2 * g].w,
                       f[2 * g + 1].x, f[2 * g + 1].y, f[2 * g + 1].z, f[2 * g + 1].w };
        u32 hiw[8], low[8];
#pragma unroll
        for (int j = 0; j < 8; ++j) {
            u32 b = __float_as_uint(e[j]);
            hiw[j] = b >> 16;                              // truncated bf16 hi
            float hf = __uint_as_float(b & 0xFFFF0000u);
            float l = e[j] - hf;                           // exact residual
            u32 bl = __float_as_uint(l);
            low[j] = (bl + 0x7FFFu + ((bl >> 16) & 1u)) >> 16;  // RNE bf16 lo
        }
        const int ln = lr + g * 16;
        uint4 qh, ql;
        qh.x = hiw[0] | (hiw[1] << 16); qh.y = hiw[2] | (hiw[3] << 16);
        qh.z = hiw[4] | (hiw[5] << 16); qh.w = hiw[6] | (hiw[7] << 16);
        ql.x = low[0] | (low[1] << 16); ql.y = low[2] | (low[3] << 16);
        ql.z = low[4] | (low[5] << 16); ql.w = low[6] | (low[7] << 16);
        *(uint4*)(base + ln * 8) = qh;
        *(uint4*)(base + 512 + ln * 8) = ql;
    }
    if (isW) {
        p += __shfl_xor(p, 1);       // pair (m,0)/(m,1) are adjacent lanes
        if (h == 0) wn[r] = p;
    }
}

// ---------------------------------------------------------------------------
// passA: grid 1024 = 16 row-supergroups (256 rows) x 64 m-groups (256 m).
// Block: 4 waves, SAME m-group, rows sg*256 + wave*64 .. +64. mg-major XCD
// mapping: XCD x streams Wc slice [x*2048, x*2048+2048) m = 1 MB (L2-fit).
// No LDS, no barriers. 2-deep named W double-buffer (static indexing).
// ---------------------------------------------------------------------------
#define LOADT(FB, WB, T) {                                                  \
    const u16* p_ = Wc + (size_t)(T) * 2048;                                \
    FB[0] = *(const bf16x8*)(p_ + lane * 8);                                \
    FB[1] = *(const bf16x8*)(p_ + 512 + lane * 8);                          \
    FB[2] = *(const bf16x8*)(p_ + 1024 + lane * 8);                         \
    FB[3] = *(const bf16x8*)(p_ + 1536 + lane * 8);                         \
    WB = wn[(T) * 16 + c15]; }

#define STEPT(FB, WB, T) {                                                  \
    f32x4 acc[4];                                                           \
    _Pragma("unroll") for (int rb = 0; rb < 4; ++rb)                        \
        acc[rb] = (f32x4){0.f, 0.f, 0.f, 0.f};                              \
    _Pragma("unroll") for (int rb = 0; rb < 4; ++rb)                        \
        acc[rb] = __builtin_amdgcn_mfma_f32_16x16x32_bf16(xh[rb][0], FB[0], acc[rb], 0, 0, 0); \
    _Pragma("unroll") for (int rb = 0; rb < 4; ++rb)                        \
        acc[rb] = __builtin_amdgcn_mfma_f32_16x16x32_bf16(xh[rb][0], FB[1], acc[rb], 0, 0, 0); \
    _Pragma("unroll") for (int rb = 0; rb < 4; ++rb)                        \
        acc[rb] = __builtin_amdgcn_mfma_f32_16x16x32_bf16(xl[rb][0], FB[0], acc[rb], 0, 0, 0); \
    _Pragma("unroll") for (int rb = 0; rb < 4; ++rb)                        \
        acc[rb] = __builtin_amdgcn_mfma_f32_16x16x32_bf16(xh[rb][1], FB[2], acc[rb], 0, 0, 0); \
    _Pragma("unroll") for (int rb = 0; rb < 4; ++rb)                        \
        acc[rb] = __builtin_amdgcn_mfma_f32_16x16x32_bf16(xh[rb][1], FB[3], acc[rb], 0, 0, 0); \
    _Pragma("unroll") for (int rb = 0; rb < 4; ++rb)                        \
        acc[rb] = __builtin_amdgcn_mfma_f32_16x16x32_bf16(xl[rb][1], FB[2], acc[rb], 0, 0, 0); \
    const int midx_ = (T) * 16 + c15;                                       \
    _Pragma("unroll") for (int rb = 0; rb < 4; ++rb)                        \
        _Pragma("unroll") for (int rg = 0; rg < 4; ++rg) {                  \
            float val = fmaf(-2.f, acc[rb][rg], WB);                        \
            bool lt_ = val < rv[rb][rg];                                    \
            rv[rb][rg] = lt_ ? val : rv[rb][rg];                            \
            rm[rb][rg] = lt_ ? midx_ : rm[rb][rg];                          \
        } }

__global__ __launch_bounds__(256, 3)
void som_passA(const u16* __restrict__ Xc, const u16* __restrict__ Wc,
               const float* __restrict__ wn, ull* __restrict__ keys) {
    const int tid = threadIdx.x;
    const int lane = tid & 63;
    const int wave = tid >> 6;
    const int bid = blockIdx.x;
    const int mg = (bid & 7) * 8 + ((bid >> 3) & 7);   // 0..63 (XCD-chunked)
    const int sg = bid >> 6;                            // 0..15
    const int row0 = sg * 256 + wave * 64;
    const int c15 = lane & 15;

    // Persistent X fragments: 4 row-blocks x 2 ksteps x (hi,lo) = 64 VGPR.
    bf16x8 xh[4][2], xl[4][2];
    {
        const bf16x8* Xf = (const bf16x8*)Xc;
#pragma unroll
        for (int rb = 0; rb < 4; ++rb) {
            const int bt = (row0 >> 4) + rb;
#pragma unroll
            for (int s = 0; s < 2; ++s) {
                xh[rb][s] = Xf[bt * 256 + s * 128 + lane];
                xl[rb][s] = Xf[bt * 256 + s * 128 + 64 + lane];
            }
        }
    }

    // Running per-lane minima (val, m) per (rb, rg). 32 VGPR.
    float rv[4][4];
    int rm[4][4];
#pragma unroll
    for (int rb = 0; rb < 4; ++rb)
#pragma unroll
        for (int rg = 0; rg < 4; ++rg) {
            rv[rb][rg] = __int_as_float(0x7F800000);  // +inf
            rm[rb][rg] = 0;
        }

    // Stream 16 m-tiles with a named 2-deep double buffer (no runtime idx).
    const int t0 = mg * 16;
    bf16x8 fA[4], fB[4];
    float wA, wB;
    LOADT(fA, wA, t0 + 0)
#pragma unroll
    for (int tp = 0; tp < 8; ++tp) {
        LOADT(fB, wB, t0 + 2 * tp + 1)
        STEPT(fA, wA, t0 + 2 * tp)
        if (tp < 7) LOADT(fA, wA, t0 + 2 * tp + 2)
        STEPT(fB, wB, t0 + 2 * tp + 1)
    }

    // Epilogue: merge cols {c, c+4, c+8, c+12} (64-m classes over 16 tiles),
    // store 256 keys/row total. C/D layout: col=lane&15, row=(lane>>4)*4+rg.
#pragma unroll
    for (int rb = 0; rb < 4; ++rb)
#pragma unroll
        for (int rg = 0; rg < 4; ++rg) {
            ull kk = ((ull)enc_f32(rv[rb][rg]) << 32) | (u32)rm[rb][rg];
            kk = umin64(kk, __shfl_xor(kk, 4));
            kk = umin64(kk, __shfl_xor(kk, 8));
            if ((lane & 12) == 0) {
                const int row = row0 + rb * 16 + ((lane >> 4) << 2) + rg;
                keys[(size_t)row * 256 + mg * 4 + (lane & 3)] = kk;
            }
        }
}

// ---------------------------------------------------------------------------
// passB: one wave per row; 256 class-winner keys/row; exact rescore within
// margin. Numerics identical to validated R4/R6 pass.
// ---------------------------------------------------------------------------
__global__ __launch_bounds__(256)
void som_passB(const float* __restrict__ X, const float* __restrict__ W,
               const ull* __restrict__ keys, int* __restrict__ out) {
    const int tid = threadIdx.x;
    const int lane = tid & 63;
    const int row = blockIdx.x * 4 + (tid >> 6);

    const ull* kr = keys + (size_t)row * 256;
    ulonglong2 pA = ((const ulonglong2*)kr)[lane];
    ulonglong2 pB = ((const ulonglong2*)kr)[lane + 64];
    ull k0 = pA.x, k1 = pA.y, k2 = pB.x, k3 = pB.y;

    ull kmin = umin64(umin64(k0, k1), umin64(k2, k3));
#pragma unroll
    for (int s = 1; s < 64; s <<= 1) kmin = umin64(kmin, __shfl_xor(kmin, s));

    float vmin = dec_f32((u32)(kmin >> 32));
    ull thr = (((ull)enc_f32(vmin + 0.05f)) << 32) | 0xFFFFFFFFull;

    float xk = X[(size_t)row * 64 + lane];
    float bestv = __int_as_float(0x7F800000);  // +inf
    int bestm = 0x7FFFFFFF;

#pragma unroll
    for (int c = 0; c < 4; ++c) {
        ull kc = (c == 0) ? k0 : (c == 1) ? k1 : (c == 2) ? k2 : k3;
        ull mask = __ballot(kc <= thr);
        while (mask) {
            int srcl = __ffsll((unsigned long long)mask) - 1;
            mask &= mask - 1;
            ull kk = __shfl(kc, srcl);
            int m = (int)(kk & 0xFFFFFFFFull);
            float wkv = W[(size_t)m * 64 + lane];
            float d = xk - wkv;
            double sq = (double)d * (double)d;
#pragma unroll
            for (int s = 1; s < 64; s <<= 1) sq += __shfl_xor(sq, s);
            float tot = (float)sq;
            float val = __fsqrt_rn(tot);
            if (val < bestv || (val == bestv && m < bestm)) {
                bestv = val;
                bestm = m;
            }
        }
    }
    if (lane == 0) {
        out[(size_t)row * 2]     = bestm >> 7;   // m / 128
        out[(size_t)row * 2 + 1] = bestm & 127;  // m % 128
    }
}

extern "C" void kernel_launch(void* const* d_in, const int* in_sizes, int n_in,
                              void* d_out, int out_size, void* d_ws, size_t ws_size,
                              hipStream_t stream) {
    const float* X = (const float*)d_in[0];   // [4096, 64]
    const float* W = (const float*)d_in[1];   // [16384, 64]
    int* out = (int*)d_out;                   // [4096, 2] int32

    char* ws = (char*)d_ws;
    u16* Xc   = (u16*)(ws);                              // 2 MB (hi+lo)
    u16* Wc   = (u16*)(ws + (2u << 20));                 // 8 MB (hi+lo)
    float* wn = (float*)(ws + (10u << 20));              // 64 KB
    ull* keys = (ull*)(ws + (10u << 20) + 65536);        // 8 MB

    som_convert<<<dim3(160), dim3(256), 0, stream>>>(X, W, Xc, Wc, wn);
    som_passA<<<dim3(1024), dim3(256), 0, stream>>>(Xc, Wc, wn, keys);
    som_passB<<<dim3(1024), dim3(256), 0, stream>>>(X, W, keys, out);
}

// Round 10
// 222.808 us; speedup vs baseline: 2.1461x; 2.1461x over previous
//
#include <hip/hip_runtime.h>
#include <stdint.h>

// SOM forward: x [4096,64] f32, weights [128,128,64] f32 -> bmus [4096,2] int32.
// Three kernels:
//   convert: X,W -> frag-ordered bf16 hi/lo tiles in d_ws + wn=||w||^2 (f32).
//   passA:   barrier-free, LDS-free MFMA streaming. Each wave: 64 rows x one
//            256-m group. X frags persistent in regs; W frags streamed from
//            L2 (4 waves/block share one m-group => L1 reuse). 3-pass hi/lo
//            bf16 split (err ~1e-4 on d^2). Per-lane running (val,m) min;
//            epilogue merges ^4,^8 -> 64-m-class winners, 256 keys/row.
//            R9 lesson: __launch_bounds__(256,3) capped VGPRs below the
//            ~170 live set -> compiler spilled persistent frags to scratch
//            (1.18 GB HBM traffic, 430us). (256,2) gives 256-VGPR budget.
//   passB:   per row, exact rescore of class winners within margin 0.05
//            (fp32 diff, fp64 square-sum, f32 sqrt), tie-break smaller m.
//            Byte-identical to the validated R4/R6 pass.

typedef unsigned short u16;
typedef unsigned int u32;
typedef unsigned long long ull;
typedef __attribute__((ext_vector_type(8))) short bf16x8;
typedef __attribute__((ext_vector_type(4))) float f32x4;

__device__ __forceinline__ u32 enc_f32(float v) {
    u32 u = __float_as_uint(v);
    return (u & 0x80000000u) ? ~u : (u | 0x80000000u);
}
__device__ __forceinline__ float dec_f32(u32 e) {
    u32 u = (e & 0x80000000u) ? (e ^ 0x80000000u) : ~e;
    return __uint_as_float(u);
}
__device__ __forceinline__ ull umin64(ull a, ull b) { return a < b ? a : b; }

// ---------------------------------------------------------------------------
// convert: unit = (row, half-of-64k). W units: 32768, X units: 8192.
// Frag layout per 16-row tile (ushort units): tile*2048 + s*1024 + p*512 +
// lane*8 + j, lane = (r&15) + ((k&31)>>3)*16, s = k>>5, j = k&7, p in {hi,lo}.
// ---------------------------------------------------------------------------
__global__ __launch_bounds__(256)
void som_convert(const float* __restrict__ X, const float* __restrict__ W,
                 u16* __restrict__ Xc, u16* __restrict__ Wc,
                 float* __restrict__ wn) {
    const int u = blockIdx.x * 256 + threadIdx.x;   // 0..40959
    const bool isW = (u < 32768);
    const int v = isW ? u : (u - 32768);
    const int r = v >> 1, h = v & 1;
    const float* src = (isW ? W : X) + (size_t)r * 64 + h * 32;
    u16* dst = isW ? Wc : Xc;

    float4 f[8];
    const float4* sp = (const float4*)src;
#pragma unroll
    for (int i = 0; i < 8; ++i) f[i] = sp[i];

    float p = 0.f;
#pragma unroll
    for (int i = 0; i < 8; ++i)
        p += f[i].x * f[i].x + f[i].y * f[i].y + f[i].z * f[i].z + f[i].w * f[i].w;

    const int bt = r >> 4, lr = r & 15, s = h;
    u16* base = dst + (size_t)bt * 2048 + s * 1024;
#pragma unroll
    for (int g = 0; g < 4; ++g) {
        float e[8] = { f[2 * g].x, f[2 * g].y, f[2 * g].z, f[2 * g].w,
                       f[2 * g + 1].x, f[2 * g + 1].y, f[2 * g + 1].z, f[2 * g + 1].w };
        u32 hiw[8], low[8];
#pragma unroll
        for (int j = 0; j < 8; ++j) {
            u32 b = __float_as_uint(e[j]);
            hiw[j] = b >> 16;                              // truncated bf16 hi
            float hf = __uint_as_float(b & 0xFFFF0000u);
            float l = e[j] - hf;                           // exact residual
            u32 bl = __float_as_uint(l);
            low[j] = (bl + 0x7FFFu + ((bl >> 16) & 1u)) >> 16;  // RNE bf16 lo
        }
        const int ln = lr + g * 16;
        uint4 qh, ql;
        qh.x = hiw[0] | (hiw[1] << 16); qh.y = hiw[2] | (hiw[3] << 16);
        qh.z = hiw[4] | (hiw[5] << 16); qh.w = hiw[6] | (hiw[7] << 16);
        ql.x = low[0] | (low[1] << 16); ql.y = low[2] | (low[3] << 16);
        ql.z = low[4] | (low[5] << 16); ql.w = low[6] | (low[7] << 16);
        *(uint4*)(base + ln * 8) = qh;
        *(uint4*)(base + 512 + ln * 8) = ql;
    }
    if (isW) {
        p += __shfl_xor(p, 1);       // pair (m,0)/(m,1) are adjacent lanes
        if (h == 0) wn[r] = p;
    }
}

// ---------------------------------------------------------------------------
// passA: grid 1024 = 16 row-supergroups (256 rows) x 64 m-groups (256 m).
// Block: 4 waves, SAME m-group, rows sg*256 + wave*64 .. +64. mg-major XCD
// mapping: XCD x streams Wc slice [x*2048, x*2048+2048) m = 1 MB (L2-fit).
// No LDS, no barriers. 2-deep named W double-buffer (static indexing).
// ---------------------------------------------------------------------------
#define LOADT(FB, WB, T) {                                                  \
    const u16* p_ = Wc + (size_t)(T) * 2048;                                \
    FB[0] = *(const bf16x8*)(p_ + lane * 8);                                \
    FB[1] = *(const bf16x8*)(p_ + 512 + lane * 8);                          \
    FB[2] = *(const bf16x8*)(p_ + 1024 + lane * 8);                         \
    FB[3] = *(const bf16x8*)(p_ + 1536 + lane * 8);                         \
    WB = wn[(T) * 16 + c15]; }

#define STEPT(FB, WB, T) {                                                  \
    f32x4 acc[4];                                                           \
    _Pragma("unroll") for (int rb = 0; rb < 4; ++rb)                        \
        acc[rb] = (f32x4){0.f, 0.f, 0.f, 0.f};                              \
    _Pragma("unroll") for (int rb = 0; rb < 4; ++rb)                        \
        acc[rb] = __builtin_amdgcn_mfma_f32_16x16x32_bf16(xh[rb][0], FB[0], acc[rb], 0, 0, 0); \
    _Pragma("unroll") for (int rb = 0; rb < 4; ++rb)                        \
        acc[rb] = __builtin_amdgcn_mfma_f32_16x16x32_bf16(xh[rb][0], FB[1], acc[rb], 0, 0, 0); \
    _Pragma("unroll") for (int rb = 0; rb < 4; ++rb)                        \
        acc[rb] = __builtin_amdgcn_mfma_f32_16x16x32_bf16(xl[rb][0], FB[0], acc[rb], 0, 0, 0); \
    _Pragma("unroll") for (int rb = 0; rb < 4; ++rb)                        \
        acc[rb] = __builtin_amdgcn_mfma_f32_16x16x32_bf16(xh[rb][1], FB[2], acc[rb], 0, 0, 0); \
    _Pragma("unroll") for (int rb = 0; rb < 4; ++rb)                        \
        acc[rb] = __builtin_amdgcn_mfma_f32_16x16x32_bf16(xh[rb][1], FB[3], acc[rb], 0, 0, 0); \
    _Pragma("unroll") for (int rb = 0; rb < 4; ++rb)                        \
        acc[rb] = __builtin_amdgcn_mfma_f32_16x16x32_bf16(xl[rb][1], FB[2], acc[rb], 0, 0, 0); \
    const int midx_ = (T) * 16 + c15;                                       \
    _Pragma("unroll") for (int rb = 0; rb < 4; ++rb)                        \
        _Pragma("unroll") for (int rg = 0; rg < 4; ++rg) {                  \
            float val = fmaf(-2.f, acc[rb][rg], WB);                        \
            bool lt_ = val < rv[rb][rg];                                    \
            rv[rb][rg] = lt_ ? val : rv[rb][rg];                            \
            rm[rb][rg] = lt_ ? midx_ : rm[rb][rg];                          \
        } }

__global__ __launch_bounds__(256, 2)
void som_passA(const u16* __restrict__ Xc, const u16* __restrict__ Wc,
               const float* __restrict__ wn, ull* __restrict__ keys) {
    const int tid = threadIdx.x;
    const int lane = tid & 63;
    const int wave = tid >> 6;
    const int bid = blockIdx.x;
    const int mg = (bid & 7) * 8 + ((bid >> 3) & 7);   // 0..63 (XCD-chunked)
    const int sg = bid >> 6;                            // 0..15
    const int row0 = sg * 256 + wave * 64;
    const int c15 = lane & 15;

    // Persistent X fragments: 4 row-blocks x 2 ksteps x (hi,lo) = 64 VGPR.
    bf16x8 xh[4][2], xl[4][2];
    {
        const bf16x8* Xf = (const bf16x8*)Xc;
#pragma unroll
        for (int rb = 0; rb < 4; ++rb) {
            const int bt = (row0 >> 4) + rb;
#pragma unroll
            for (int s = 0; s < 2; ++s) {
                xh[rb][s] = Xf[bt * 256 + s * 128 + lane];
                xl[rb][s] = Xf[bt * 256 + s * 128 + 64 + lane];
            }
        }
    }

    // Running per-lane minima (val, m) per (rb, rg). 32 VGPR.
    float rv[4][4];
    int rm[4][4];
#pragma unroll
    for (int rb = 0; rb < 4; ++rb)
#pragma unroll
        for (int rg = 0; rg < 4; ++rg) {
            rv[rb][rg] = __int_as_float(0x7F800000);  // +inf
            rm[rb][rg] = 0;
        }

    // Stream 16 m-tiles with a named 2-deep double buffer (no runtime idx).
    const int t0 = mg * 16;
    bf16x8 fA[4], fB[4];
    float wA, wB;
    LOADT(fA, wA, t0 + 0)
#pragma unroll
    for (int tp = 0; tp < 8; ++tp) {
        LOADT(fB, wB, t0 + 2 * tp + 1)
        STEPT(fA, wA, t0 + 2 * tp)
        if (tp < 7) LOADT(fA, wA, t0 + 2 * tp + 2)
        STEPT(fB, wB, t0 + 2 * tp + 1)
    }

    // Epilogue: merge cols {c, c+4, c+8, c+12} (64-m classes over 16 tiles),
    // store 256 keys/row total. C/D layout: col=lane&15, row=(lane>>4)*4+rg.
#pragma unroll
    for (int rb = 0; rb < 4; ++rb)
#pragma unroll
        for (int rg = 0; rg < 4; ++rg) {
            ull kk = ((ull)enc_f32(rv[rb][rg]) << 32) | (u32)rm[rb][rg];
            kk = umin64(kk, __shfl_xor(kk, 4));
            kk = umin64(kk, __shfl_xor(kk, 8));
            if ((lane & 12) == 0) {
                const int row = row0 + rb * 16 + ((lane >> 4) << 2) + rg;
                keys[(size_t)row * 256 + mg * 4 + (lane & 3)] = kk;
            }
        }
}

// ---------------------------------------------------------------------------
// passB: one wave per row; 256 class-winner keys/row; exact rescore within
// margin. Numerics identical to validated R4/R6 pass.
// ---------------------------------------------------------------------------
__global__ __launch_bounds__(256)
void som_passB(const float* __restrict__ X, const float* __restrict__ W,
               const ull* __restrict__ keys, int* __restrict__ out) {
    const int tid = threadIdx.x;
    const int lane = tid & 63;
    const int row = blockIdx.x * 4 + (tid >> 6);

    const ull* kr = keys + (size_t)row * 256;
    ulonglong2 pA = ((const ulonglong2*)kr)[lane];
    ulonglong2 pB = ((const ulonglong2*)kr)[lane + 64];
    ull k0 = pA.x, k1 = pA.y, k2 = pB.x, k3 = pB.y;

    ull kmin = umin64(umin64(k0, k1), umin64(k2, k3));
#pragma unroll
    for (int s = 1; s < 64; s <<= 1) kmin = umin64(kmin, __shfl_xor(kmin, s));

    float vmin = dec_f32((u32)(kmin >> 32));
    ull thr = (((ull)enc_f32(vmin + 0.05f)) << 32) | 0xFFFFFFFFull;

    float xk = X[(size_t)row * 64 + lane];
    float bestv = __int_as_float(0x7F800000);  // +inf
    int bestm = 0x7FFFFFFF;

#pragma unroll
    for (int c = 0; c < 4; ++c) {
        ull kc = (c == 0) ? k0 : (c == 1) ? k1 : (c == 2) ? k2 : k3;
        ull mask = __ballot(kc <= thr);
        while (mask) {
            int srcl = __ffsll((unsigned long long)mask) - 1;
            mask &= mask - 1;
            ull kk = __shfl(kc, srcl);
            int m = (int)(kk & 0xFFFFFFFFull);
            float wkv = W[(size_t)m * 64 + lane];
            float d = xk - wkv;
            double sq = (double)d * (double)d;
#pragma unroll
            for (int s = 1; s < 64; s <<= 1) sq += __shfl_xor(sq, s);
            float tot = (float)sq;
            float val = __fsqrt_rn(tot);
            if (val < bestv || (val == bestv && m < bestm)) {
                bestv = val;
                bestm = m;
            }
        }
    }
    if (lane == 0) {
        out[(size_t)row * 2]     = bestm >> 7;   // m / 128
        out[(size_t)row * 2 + 1] = bestm & 127;  // m % 128
    }
}

extern "C" void kernel_launch(void* const* d_in, const int* in_sizes, int n_in,
                              void* d_out, int out_size, void* d_ws, size_t ws_size,
                              hipStream_t stream) {
    const float* X = (const float*)d_in[0];   // [4096, 64]
    const float* W = (const float*)d_in[1];   // [16384, 64]
    int* out = (int*)d_out;                   // [4096, 2] int32

    char* ws = (char*)d_ws;
    u16* Xc   = (u16*)(ws);                              // 2 MB (hi+lo)
    u16* Wc   = (u16*)(ws + (2u << 20));                 // 8 MB (hi+lo)
    float* wn = (float*)(ws + (10u << 20));              // 64 KB
    ull* keys = (ull*)(ws + (10u << 20) + 65536);        // 8 MB

    som_convert<<<dim3(160), dim3(256), 0, stream>>>(X, W, Xc, Wc, wn);
    som_passA<<<dim3(1024), dim3(256), 0, stream>>>(Xc, Wc, wn, keys);
    som_passB<<<dim3(1024), dim3(256), 0, stream>>>(X, W, keys, out);
}

// Round 12
// 126.418 us; speedup vs baseline: 3.7825x; 1.7625x over previous
//
#include <hip/hip_runtime.h>
#include <stdint.h>

// SOM forward: x [4096,64] f32, weights [128,128,64] f32 -> bmus [4096,2] int32.
// Three kernels:
//   convert: X,W -> frag-ordered bf16 hi/lo tiles in d_ws + wn=||w||^2 (f32).
//   passA:   barrier-free, LDS-free MFMA streaming. Each wave: 32 rows x one
//            256-m group. X frags persistent in regs; W frags streamed from
//            L2. 3-pass hi/lo bf16 split (err ~1e-4 on d^2). Per-lane running
//            (val,m) min; epilogue merges ^4,^8 -> 64-m-class winners,
//            256 keys/row.
//            R9/R10 lesson: __launch_bounds__(256,N) granted 512/(2N) VGPRs
//            (84 at N=3, 128 at N=2) -> spill -> 0.6-1.2 GB scratch traffic.
//            Fix: maxthreads-only bound (default allocator, no spill through
//            ~450 regs per m08) + live set shrunk to ~105 VGPR (2 row-blocks).
//   passB:   per row, exact rescore of class winners within margin 0.05
//            (fp32 diff, fp64 square-sum, f32 sqrt), tie-break smaller m.
//            Byte-identical to the validated R4/R6 pass.

typedef unsigned short u16;
typedef unsigned int u32;
typedef unsigned long long ull;
typedef __attribute__((ext_vector_type(8))) short bf16x8;
typedef __attribute__((ext_vector_type(4))) float f32x4;

__device__ __forceinline__ u32 enc_f32(float v) {
    u32 u = __float_as_uint(v);
    return (u & 0x80000000u) ? ~u : (u | 0x80000000u);
}
__device__ __forceinline__ float dec_f32(u32 e) {
    u32 u = (e & 0x80000000u) ? (e ^ 0x80000000u) : ~e;
    return __uint_as_float(u);
}
__device__ __forceinline__ ull umin64(ull a, ull b) { return a < b ? a : b; }

// ---------------------------------------------------------------------------
// convert: unit = (row, half-of-64k). W units: 32768, X units: 8192.
// Frag layout per 16-row tile (ushort units): tile*2048 + s*1024 + p*512 +
// lane*8 + j, lane = (r&15) + ((k&31)>>3)*16, s = k>>5, j = k&7, p in {hi,lo}.
// ---------------------------------------------------------------------------
__global__ __launch_bounds__(256)
void som_convert(const float* __restrict__ X, const float* __restrict__ W,
                 u16* __restrict__ Xc, u16* __restrict__ Wc,
                 float* __restrict__ wn) {
    const int u = blockIdx.x * 256 + threadIdx.x;   // 0..40959
    const bool isW = (u < 32768);
    const int v = isW ? u : (u - 32768);
    const int r = v >> 1, h = v & 1;
    const float* src = (isW ? W : X) + (size_t)r * 64 + h * 32;
    u16* dst = isW ? Wc : Xc;

    float4 f[8];
    const float4* sp = (const float4*)src;
#pragma unroll
    for (int i = 0; i < 8; ++i) f[i] = sp[i];

    float p = 0.f;
#pragma unroll
    for (int i = 0; i < 8; ++i)
        p += f[i].x * f[i].x + f[i].y * f[i].y + f[i].z * f[i].z + f[i].w * f[i].w;

    const int bt = r >> 4, lr = r & 15, s = h;
    u16* base = dst + (size_t)bt * 2048 + s * 1024;
#pragma unroll
    for (int g = 0; g < 4; ++g) {
        float e[8] = { f[2 * g].x, f[2 * g].y, f[2 * g].z, f[2 * g].w,
                       f[2 * g + 1].x, f[2 * g + 1].y, f[2 * g + 1].z, f[2 * g + 1].w };
        u32 hiw[8], low[8];
#pragma unroll
        for (int j = 0; j < 8; ++j) {
            u32 b = __float_as_uint(e[j]);
            hiw[j] = b >> 16;                              // truncated bf16 hi
            float hf = __uint_as_float(b & 0xFFFF0000u);
            float l = e[j] - hf;                           // exact residual
            u32 bl = __float_as_uint(l);
            low[j] = (bl + 0x7FFFu + ((bl >> 16) & 1u)) >> 16;  // RNE bf16 lo
        }
        const int ln = lr + g * 16;
        uint4 qh, ql;
        qh.x = hiw[0] | (hiw[1] << 16); qh.y = hiw[2] | (hiw[3] << 16);
        qh.z = hiw[4] | (hiw[5] << 16); qh.w = hiw[6] | (hiw[7] << 16);
        ql.x = low[0] | (low[1] << 16); ql.y = low[2] | (low[3] << 16);
        ql.z = low[4] | (low[5] << 16); ql.w = low[6] | (low[7] << 16);
        *(uint4*)(base + ln * 8) = qh;
        *(uint4*)(base + 512 + ln * 8) = ql;
    }
    if (isW) {
        p += __shfl_xor(p, 1);       // pair (m,0)/(m,1) are adjacent lanes
        if (h == 0) wn[r] = p;
    }
}

// ---------------------------------------------------------------------------
// passA: grid 2048 = 32 row-supergroups (128 rows) x 64 m-groups (256 m).
// Block: 4 waves, SAME m-group, rows sg*128 + wave*32 .. +32. mg-major XCD
// mapping: XCD x streams Wc slices for mgs [8x, 8x+8) = 512 KB (L2-fit).
// No LDS, no barriers. 2-deep named W double-buffer (static indexing).
// ---------------------------------------------------------------------------
#define LOADT(FB, WB, T) {                                                  \
    const u16* p_ = Wc + (size_t)(T) * 2048;                                \
    FB[0] = *(const bf16x8*)(p_ + lane * 8);                                \
    FB[1] = *(const bf16x8*)(p_ + 512 + lane * 8);                          \
    FB[2] = *(const bf16x8*)(p_ + 1024 + lane * 8);                         \
    FB[3] = *(const bf16x8*)(p_ + 1536 + lane * 8);                         \
    WB = wn[(T) * 16 + c15]; }

#define STEPT(FB, WB, T) {                                                  \
    f32x4 acc[2];                                                           \
    _Pragma("unroll") for (int rb = 0; rb < 2; ++rb)                        \
        acc[rb] = (f32x4){0.f, 0.f, 0.f, 0.f};                              \
    _Pragma("unroll") for (int rb = 0; rb < 2; ++rb)                        \
        acc[rb] = __builtin_amdgcn_mfma_f32_16x16x32_bf16(xh[rb][0], FB[0], acc[rb], 0, 0, 0); \
    _Pragma("unroll") for (int rb = 0; rb < 2; ++rb)                        \
        acc[rb] = __builtin_amdgcn_mfma_f32_16x16x32_bf16(xh[rb][0], FB[1], acc[rb], 0, 0, 0); \
    _Pragma("unroll") for (int rb = 0; rb < 2; ++rb)                        \
        acc[rb] = __builtin_amdgcn_mfma_f32_16x16x32_bf16(xl[rb][0], FB[0], acc[rb], 0, 0, 0); \
    _Pragma("unroll") for (int rb = 0; rb < 2; ++rb)                        \
        acc[rb] = __builtin_amdgcn_mfma_f32_16x16x32_bf16(xh[rb][1], FB[2], acc[rb], 0, 0, 0); \
    _Pragma("unroll") for (int rb = 0; rb < 2; ++rb)                        \
        acc[rb] = __builtin_amdgcn_mfma_f32_16x16x32_bf16(xh[rb][1], FB[3], acc[rb], 0, 0, 0); \
    _Pragma("unroll") for (int rb = 0; rb < 2; ++rb)                        \
        acc[rb] = __builtin_amdgcn_mfma_f32_16x16x32_bf16(xl[rb][1], FB[2], acc[rb], 0, 0, 0); \
    const int midx_ = (T) * 16 + c15;                                       \
    _Pragma("unroll") for (int rb = 0; rb < 2; ++rb)                        \
        _Pragma("unroll") for (int rg = 0; rg < 4; ++rg) {                  \
            float val = fmaf(-2.f, acc[rb][rg], WB);                        \
            bool lt_ = val < rv[rb][rg];                                    \
            rv[rb][rg] = lt_ ? val : rv[rb][rg];                            \
            rm[rb][rg] = lt_ ? midx_ : rm[rb][rg];                          \
        } }

__global__ __launch_bounds__(256)
void som_passA(const u16* __restrict__ Xc, const u16* __restrict__ Wc,
               const float* __restrict__ wn, ull* __restrict__ keys) {
    const int tid = threadIdx.x;
    const int lane = tid & 63;
    const int wave = tid >> 6;
    const int bid = blockIdx.x;
    const int mg = (bid & 7) * 8 + ((bid >> 3) & 7);   // 0..63 (XCD-chunked)
    const int sg = bid >> 6;                            // 0..31
    const int row0 = sg * 128 + wave * 32;
    const int c15 = lane & 15;

    // Persistent X fragments: 2 row-blocks x 2 ksteps x (hi,lo) = 32 VGPR.
    bf16x8 xh[2][2], xl[2][2];
    {
        const bf16x8* Xf = (const bf16x8*)Xc;
#pragma unroll
        for (int rb = 0; rb < 2; ++rb) {
            const int bt = (row0 >> 4) + rb;
#pragma unroll
            for (int s = 0; s < 2; ++s) {
                xh[rb][s] = Xf[bt * 256 + s * 128 + lane];
                xl[rb][s] = Xf[bt * 256 + s * 128 + 64 + lane];
            }
        }
    }

    // Running per-lane minima (val, m) per (rb, rg). 16 VGPR.
    float rv[2][4];
    int rm[2][4];
#pragma unroll
    for (int rb = 0; rb < 2; ++rb)
#pragma unroll
        for (int rg = 0; rg < 4; ++rg) {
            rv[rb][rg] = __int_as_float(0x7F800000);  // +inf
            rm[rb][rg] = 0;
        }

    // Stream 16 m-tiles with a named 2-deep double buffer (no runtime idx).
    const int t0 = mg * 16;
    bf16x8 fA[4], fB[4];
    float wA, wB;
    LOADT(fA, wA, t0 + 0)
#pragma unroll
    for (int tp = 0; tp < 8; ++tp) {
        LOADT(fB, wB, t0 + 2 * tp + 1)
        STEPT(fA, wA, t0 + 2 * tp)
        if (tp < 7) LOADT(fA, wA, t0 + 2 * tp + 2)
        STEPT(fB, wB, t0 + 2 * tp + 1)
    }

    // Epilogue: merge cols {c, c+4, c+8, c+12} (64-m classes over 16 tiles),
    // store 256 keys/row total. C/D layout: col=lane&15, row=(lane>>4)*4+rg.
#pragma unroll
    for (int rb = 0; rb < 2; ++rb)
#pragma unroll
        for (int rg = 0; rg < 4; ++rg) {
            ull kk = ((ull)enc_f32(rv[rb][rg]) << 32) | (u32)rm[rb][rg];
            kk = umin64(kk, __shfl_xor(kk, 4));
            kk = umin64(kk, __shfl_xor(kk, 8));
            if ((lane & 12) == 0) {
                const int row = row0 + rb * 16 + ((lane >> 4) << 2) + rg;
                keys[(size_t)row * 256 + mg * 4 + (lane & 3)] = kk;
            }
        }
}

// ---------------------------------------------------------------------------
// passB: one wave per row; 256 class-winner keys/row; exact rescore within
// margin. Numerics identical to validated R4/R6 pass.
// ---------------------------------------------------------------------------
__global__ __launch_bounds__(256)
void som_passB(const float* __restrict__ X, const float* __restrict__ W,
               const ull* __restrict__ keys, int* __restrict__ out) {
    const int tid = threadIdx.x;
    const int lane = tid & 63;
    const int row = blockIdx.x * 4 + (tid >> 6);

    const ull* kr = keys + (size_t)row * 256;
    ulonglong2 pA = ((const ulonglong2*)kr)[lane];
    ulonglong2 pB = ((const ulonglong2*)kr)[lane + 64];
    ull k0 = pA.x, k1 = pA.y, k2 = pB.x, k3 = pB.y;

    ull kmin = umin64(umin64(k0, k1), umin64(k2, k3));
#pragma unroll
    for (int s = 1; s < 64; s <<= 1) kmin = umin64(kmin, __shfl_xor(kmin, s));

    float vmin = dec_f32((u32)(kmin >> 32));
    ull thr = (((ull)enc_f32(vmin + 0.05f)) << 32) | 0xFFFFFFFFull;

    float xk = X[(size_t)row * 64 + lane];
    float bestv = __int_as_float(0x7F800000);  // +inf
    int bestm = 0x7FFFFFFF;

#pragma unroll
    for (int c = 0; c < 4; ++c) {
        ull kc = (c == 0) ? k0 : (c == 1) ? k1 : (c == 2) ? k2 : k3;
        ull mask = __ballot(kc <= thr);
        while (mask) {
            int srcl = __ffsll((unsigned long long)mask) - 1;
            mask &= mask - 1;
            ull kk = __shfl(kc, srcl);
            int m = (int)(kk & 0xFFFFFFFFull);
            float wkv = W[(size_t)m * 64 + lane];
            float d = xk - wkv;
            double sq = (double)d * (double)d;
#pragma unroll
            for (int s = 1; s < 64; s <<= 1) sq += __shfl_xor(sq, s);
            float tot = (float)sq;
            float val = __fsqrt_rn(tot);
            if (val < bestv || (val == bestv && m < bestm)) {
                bestv = val;
                bestm = m;
            }
        }
    }
    if (lane == 0) {
        out[(size_t)row * 2]     = bestm >> 7;   // m / 128
        out[(size_t)row * 2 + 1] = bestm & 127;  // m % 128
    }
}

extern "C" void kernel_launch(void* const* d_in, const int* in_sizes, int n_in,
                              void* d_out, int out_size, void* d_ws, size_t ws_size,
                              hipStream_t stream) {
    const float* X = (const float*)d_in[0];   // [4096, 64]
    const float* W = (const float*)d_in[1];   // [16384, 64]
    int* out = (int*)d_out;                   // [4096, 2] int32

    char* ws = (char*)d_ws;
    u16* Xc   = (u16*)(ws);                              // 2 MB (hi+lo)
    u16* Wc   = (u16*)(ws + (2u << 20));                 // 8 MB (hi+lo)
    float* wn = (float*)(ws + (10u << 20));              // 64 KB
    ull* keys = (ull*)(ws + (10u << 20) + 65536);        // 8 MB

    som_convert<<<dim3(160), dim3(256), 0, stream>>>(X, W, Xc, Wc, wn);
    som_passA<<<dim3(2048), dim3(256), 0, stream>>>(Xc, Wc, wn, keys);
    som_passB<<<dim3(1024), dim3(256), 0, stream>>>(X, W, keys, out);
}

// Round 13
// 109.235 us; speedup vs baseline: 4.3775x; 1.1573x over previous
//
#include <hip/hip_runtime.h>
#include <stdint.h>

// SOM forward: x [4096,64] f32, weights [128,128,64] f32 -> bmus [4096,2] int32.
// Three kernels:
//   convert: X,W -> frag-ordered bf16 hi/lo tiles in d_ws + wn=||w||^2 (f32).
//   passA:   barrier-free, LDS-free MFMA streaming. Each wave: 32 rows x one
//            256-m group. X frags persistent in regs; W streamed from L2 with
//            a 3-deep register prefetch ring. 3-pass hi/lo bf16 split
//            (err ~1e-4 on d^2). Per-lane running (val,m) min; epilogue
//            merges ^4,^8 -> 64-m-class winners, 256 keys/row.
//            R9/R10: __launch_bounds__(256,N) empirically grants 512/(2N)
//            VGPRs (N=2 -> 128, N=3 -> 84). R12: default bound -> 152 VGPR
//            -> only 2 waves/SIMD -> latency-bound at 63us (MfmaUtil 15%).
//            R13: live set ~115 < 128, so (256,2) gives 4 waves/SIMD with
//            no spill + 3-deep ring for in-wave latency hiding.
//   passB:   per row, exact rescore of class winners within margin 0.05
//            (fp32 diff, fp64 square-sum, f32 sqrt), tie-break smaller m.
//            Byte-identical to the validated R4/R6 pass.

typedef unsigned short u16;
typedef unsigned int u32;
typedef unsigned long long ull;
typedef __attribute__((ext_vector_type(8))) short bf16x8;
typedef __attribute__((ext_vector_type(4))) float f32x4;

__device__ __forceinline__ u32 enc_f32(float v) {
    u32 u = __float_as_uint(v);
    return (u & 0x80000000u) ? ~u : (u | 0x80000000u);
}
__device__ __forceinline__ float dec_f32(u32 e) {
    u32 u = (e & 0x80000000u) ? (e ^ 0x80000000u) : ~e;
    return __uint_as_float(u);
}
__device__ __forceinline__ ull umin64(ull a, ull b) { return a < b ? a : b; }

// ---------------------------------------------------------------------------
// convert: unit = (row, half-of-64k). W units: 32768, X units: 8192.
// Frag layout per 16-row tile (ushort units): tile*2048 + s*1024 + p*512 +
// lane*8 + j, lane = (r&15) + ((k&31)>>3)*16, s = k>>5, j = k&7, p in {hi,lo}.
// ---------------------------------------------------------------------------
__global__ __launch_bounds__(256)
void som_convert(const float* __restrict__ X, const float* __restrict__ W,
                 u16* __restrict__ Xc, u16* __restrict__ Wc,
                 float* __restrict__ wn) {
    const int u = blockIdx.x * 256 + threadIdx.x;   // 0..40959
    const bool isW = (u < 32768);
    const int v = isW ? u : (u - 32768);
    const int r = v >> 1, h = v & 1;
    const float* src = (isW ? W : X) + (size_t)r * 64 + h * 32;
    u16* dst = isW ? Wc : Xc;

    float4 f[8];
    const float4* sp = (const float4*)src;
#pragma unroll
    for (int i = 0; i < 8; ++i) f[i] = sp[i];

    float p = 0.f;
#pragma unroll
    for (int i = 0; i < 8; ++i)
        p += f[i].x * f[i].x + f[i].y * f[i].y + f[i].z * f[i].z + f[i].w * f[i].w;

    const int bt = r >> 4, lr = r & 15, s = h;
    u16* base = dst + (size_t)bt * 2048 + s * 1024;
#pragma unroll
    for (int g = 0; g < 4; ++g) {
        float e[8] = { f[2 * g].x, f[2 * g].y, f[2 * g].z, f[2 * g].w,
                       f[2 * g + 1].x, f[2 * g + 1].y, f[2 * g + 1].z, f[2 * g + 1].w };
        u32 hiw[8], low[8];
#pragma unroll
        for (int j = 0; j < 8; ++j) {
            u32 b = __float_as_uint(e[j]);
            hiw[j] = b >> 16;                              // truncated bf16 hi
            float hf = __uint_as_float(b & 0xFFFF0000u);
            float l = e[j] - hf;                           // exact residual
            u32 bl = __float_as_uint(l);
            low[j] = (bl + 0x7FFFu + ((bl >> 16) & 1u)) >> 16;  // RNE bf16 lo
        }
        const int ln = lr + g * 16;
        uint4 qh, ql;
        qh.x = hiw[0] | (hiw[1] << 16); qh.y = hiw[2] | (hiw[3] << 16);
        qh.z = hiw[4] | (hiw[5] << 16); qh.w = hiw[6] | (hiw[7] << 16);
        ql.x = low[0] | (low[1] << 16); ql.y = low[2] | (low[3] << 16);
        ql.z = low[4] | (low[5] << 16); ql.w = low[6] | (low[7] << 16);
        *(uint4*)(base + ln * 8) = qh;
        *(uint4*)(base + 512 + ln * 8) = ql;
    }
    if (isW) {
        p += __shfl_xor(p, 1);       // pair (m,0)/(m,1) are adjacent lanes
        if (h == 0) wn[r] = p;
    }
}

// ---------------------------------------------------------------------------
// passA: grid 2048 = 32 row-supergroups (128 rows) x 64 m-groups (256 m).
// Block: 4 waves, SAME m-group, rows sg*128 + wave*32 .. +32. mg-major XCD
// mapping (bid%8 = XCD round-robin): XCD x streams Wc slices for mgs
// [8x, 8x+8) = 512 KB (L2-fit). No LDS, no barriers.
// 3-deep named register prefetch ring (static indexing, rule #20).
// ---------------------------------------------------------------------------
#define LOADT(FB, WB, T) {                                                  \
    const u16* p_ = Wc + (size_t)(T) * 2048;                                \
    FB[0] = *(const bf16x8*)(p_ + lane * 8);                                \
    FB[1] = *(const bf16x8*)(p_ + 512 + lane * 8);                          \
    FB[2] = *(const bf16x8*)(p_ + 1024 + lane * 8);                         \
    FB[3] = *(const bf16x8*)(p_ + 1536 + lane * 8);                         \
    WB = wn[(T) * 16 + c15]; }

#define STEPT(FB, WB, T) {                                                  \
    f32x4 acc[2];                                                           \
    _Pragma("unroll") for (int rb = 0; rb < 2; ++rb)                        \
        acc[rb] = (f32x4){0.f, 0.f, 0.f, 0.f};                              \
    _Pragma("unroll") for (int rb = 0; rb < 2; ++rb)                        \
        acc[rb] = __builtin_amdgcn_mfma_f32_16x16x32_bf16(xh[rb][0], FB[0], acc[rb], 0, 0, 0); \
    _Pragma("unroll") for (int rb = 0; rb < 2; ++rb)                        \
        acc[rb] = __builtin_amdgcn_mfma_f32_16x16x32_bf16(xh[rb][0], FB[1], acc[rb], 0, 0, 0); \
    _Pragma("unroll") for (int rb = 0; rb < 2; ++rb)                        \
        acc[rb] = __builtin_amdgcn_mfma_f32_16x16x32_bf16(xl[rb][0], FB[0], acc[rb], 0, 0, 0); \
    _Pragma("unroll") for (int rb = 0; rb < 2; ++rb)                        \
        acc[rb] = __builtin_amdgcn_mfma_f32_16x16x32_bf16(xh[rb][1], FB[2], acc[rb], 0, 0, 0); \
    _Pragma("unroll") for (int rb = 0; rb < 2; ++rb)                        \
        acc[rb] = __builtin_amdgcn_mfma_f32_16x16x32_bf16(xh[rb][1], FB[3], acc[rb], 0, 0, 0); \
    _Pragma("unroll") for (int rb = 0; rb < 2; ++rb)                        \
        acc[rb] = __builtin_amdgcn_mfma_f32_16x16x32_bf16(xl[rb][1], FB[2], acc[rb], 0, 0, 0); \
    const int midx_ = (T) * 16 + c15;                                       \
    _Pragma("unroll") for (int rb = 0; rb < 2; ++rb)                        \
        _Pragma("unroll") for (int rg = 0; rg < 4; ++rg) {                  \
            float val = fmaf(-2.f, acc[rb][rg], WB);                        \
            bool lt_ = val < rv[rb][rg];                                    \
            rv[rb][rg] = lt_ ? val : rv[rb][rg];                            \
            rm[rb][rg] = lt_ ? midx_ : rm[rb][rg];                          \
        } }

__global__ __launch_bounds__(256, 2)   // empirical: grants 128 VGPR -> 4 waves/SIMD
void som_passA(const u16* __restrict__ Xc, const u16* __restrict__ Wc,
               const float* __restrict__ wn, ull* __restrict__ keys) {
    const int tid = threadIdx.x;
    const int lane = tid & 63;
    const int wave = tid >> 6;
    const int bid = blockIdx.x;
    const int mg = (bid & 7) * 8 + ((bid >> 3) & 7);   // 0..63 (XCD-chunked)
    const int sg = bid >> 6;                            // 0..31
    const int row0 = sg * 128 + wave * 32;
    const int c15 = lane & 15;

    // Persistent X fragments: 2 row-blocks x 2 ksteps x (hi,lo) = 32 VGPR.
    bf16x8 xh[2][2], xl[2][2];
    {
        const bf16x8* Xf = (const bf16x8*)Xc;
#pragma unroll
        for (int rb = 0; rb < 2; ++rb) {
            const int bt = (row0 >> 4) + rb;
#pragma unroll
            for (int s = 0; s < 2; ++s) {
                xh[rb][s] = Xf[bt * 256 + s * 128 + lane];
                xl[rb][s] = Xf[bt * 256 + s * 128 + 64 + lane];
            }
        }
    }

    // Running per-lane minima (val, m) per (rb, rg). 16 VGPR.
    float rv[2][4];
    int rm[2][4];
#pragma unroll
    for (int rb = 0; rb < 2; ++rb)
#pragma unroll
        for (int rg = 0; rg < 4; ++rg) {
            rv[rb][rg] = __int_as_float(0x7F800000);  // +inf
            rm[rb][rg] = 0;
        }

    // Stream 16 m-tiles with a 3-deep named prefetch ring (no runtime idx).
    const int t0 = mg * 16;
    bf16x8 fA[4], fB[4], fC[4];
    float wA, wB, wC;
    LOADT(fA, wA, t0 + 0)
    LOADT(fB, wB, t0 + 1)
#pragma unroll
    for (int r = 0; r < 5; ++r) {
        LOADT(fC, wC, t0 + 3 * r + 2)
        STEPT(fA, wA, t0 + 3 * r)
        if (3 * r + 3 < 16) LOADT(fA, wA, t0 + 3 * r + 3)
        STEPT(fB, wB, t0 + 3 * r + 1)
        if (3 * r + 4 < 16) LOADT(fB, wB, t0 + 3 * r + 4)
        STEPT(fC, wC, t0 + 3 * r + 2)
    }
    STEPT(fA, wA, t0 + 15)

    // Epilogue: merge cols {c, c+4, c+8, c+12} (64-m classes over 16 tiles),
    // store 256 keys/row total. C/D layout: col=lane&15, row=(lane>>4)*4+rg.
#pragma unroll
    for (int rb = 0; rb < 2; ++rb)
#pragma unroll
        for (int rg = 0; rg < 4; ++rg) {
            ull kk = ((ull)enc_f32(rv[rb][rg]) << 32) | (u32)rm[rb][rg];
            kk = umin64(kk, __shfl_xor(kk, 4));
            kk = umin64(kk, __shfl_xor(kk, 8));
            if ((lane & 12) == 0) {
                const int row = row0 + rb * 16 + ((lane >> 4) << 2) + rg;
                keys[(size_t)row * 256 + mg * 4 + (lane & 3)] = kk;
            }
        }
}

// ---------------------------------------------------------------------------
// passB: one wave per row; 256 class-winner keys/row; exact rescore within
// margin. Numerics identical to validated R4/R6 pass.
// ---------------------------------------------------------------------------
__global__ __launch_bounds__(256)
void som_passB(const float* __restrict__ X, const float* __restrict__ W,
               const ull* __restrict__ keys, int* __restrict__ out) {
    const int tid = threadIdx.x;
    const int lane = tid & 63;
    const int row = blockIdx.x * 4 + (tid >> 6);

    const ull* kr = keys + (size_t)row * 256;
    ulonglong2 pA = ((const ulonglong2*)kr)[lane];
    ulonglong2 pB = ((const ulonglong2*)kr)[lane + 64];
    ull k0 = pA.x, k1 = pA.y, k2 = pB.x, k3 = pB.y;

    ull kmin = umin64(umin64(k0, k1), umin64(k2, k3));
#pragma unroll
    for (int s = 1; s < 64; s <<= 1) kmin = umin64(kmin, __shfl_xor(kmin, s));

    float vmin = dec_f32((u32)(kmin >> 32));
    ull thr = (((ull)enc_f32(vmin + 0.05f)) << 32) | 0xFFFFFFFFull;

    float xk = X[(size_t)row * 64 + lane];
    float bestv = __int_as_float(0x7F800000);  // +inf
    int bestm = 0x7FFFFFFF;

#pragma unroll
    for (int c = 0; c < 4; ++c) {
        ull kc = (c == 0) ? k0 : (c == 1) ? k1 : (c == 2) ? k2 : k3;
        ull mask = __ballot(kc <= thr);
        while (mask) {
            int srcl = __ffsll((unsigned long long)mask) - 1;
            mask &= mask - 1;
            ull kk = __shfl(kc, srcl);
            int m = (int)(kk & 0xFFFFFFFFull);
            float wkv = W[(size_t)m * 64 + lane];
            float d = xk - wkv;
            double sq = (double)d * (double)d;
#pragma unroll
            for (int s = 1; s < 64; s <<= 1) sq += __shfl_xor(sq, s);
            float tot = (float)sq;
            float val = __fsqrt_rn(tot);
            if (val < bestv || (val == bestv && m < bestm)) {
                bestv = val;
                bestm = m;
            }
        }
    }
    if (lane == 0) {
        out[(size_t)row * 2]     = bestm >> 7;   // m / 128
        out[(size_t)row * 2 + 1] = bestm & 127;  // m % 128
    }
}

extern "C" void kernel_launch(void* const* d_in, const int* in_sizes, int n_in,
                              void* d_out, int out_size, void* d_ws, size_t ws_size,
                              hipStream_t stream) {
    const float* X = (const float*)d_in[0];   // [4096, 64]
    const float* W = (const float*)d_in[1];   // [16384, 64]
    int* out = (int*)d_out;                   // [4096, 2] int32

    char* ws = (char*)d_ws;
    u16* Xc   = (u16*)(ws);                              // 2 MB (hi+lo)
    u16* Wc   = (u16*)(ws + (2u << 20));                 // 8 MB (hi+lo)
    float* wn = (float*)(ws + (10u << 20));              // 64 KB
    ull* keys = (ull*)(ws + (10u << 20) + 65536);        // 8 MB

    som_convert<<<dim3(160), dim3(256), 0, stream>>>(X, W, Xc, Wc, wn);
    som_passA<<<dim3(2048), dim3(256), 0, stream>>>(Xc, Wc, wn, keys);
    som_passB<<<dim3(1024), dim3(256), 0, stream>>>(X, W, keys, out);
}